// Round 4
// baseline (150.363 us; speedup 1.0000x reference)
//
#include <hip/hip_runtime.h>

// firing_model: reference scan starts at the zero vector and
// nxt = -prev + tanh(prev @ x) fixes zero — output is exactly zeros.
// Kernel = streaming zero-fill of d_out (137.9 MB), write-BW bound.
//
// R2 evidence: hipMemsetAsync and the naive 1-float4/thread fill both run
// ~4.5 TB/s on this 137.9 MB buffer, while the harness's 551.8 MB poison
// fill sustains 6.6 TB/s. Attack the gap with (a) nontemporal stores (no
// cache allocation for a write-once stream) and (b) grid-stride unroll x4.
//
// R3 fix: __builtin_nontemporal_store requires a native clang vector type,
// not HIP's float4 class — use ext_vector_type(4) float.

typedef float vfloat4 __attribute__((ext_vector_type(4)));

__global__ __launch_bounds__(256) void firing_model_zero_fill_nt(vfloat4* __restrict__ out4,
                                                                 long long n4) {
    const long long stride = (long long)gridDim.x * blockDim.x;
    long long i = (long long)blockIdx.x * blockDim.x + threadIdx.x;
    const vfloat4 z = {0.f, 0.f, 0.f, 0.f};

    // Unrolled-by-4 grid-stride: 4 independent dwordx4 nt stores per iter.
    long long limit = n4 - 3 * stride;
    for (; i < limit; i += 4 * stride) {
        __builtin_nontemporal_store(z, &out4[i]);
        __builtin_nontemporal_store(z, &out4[i + stride]);
        __builtin_nontemporal_store(z, &out4[i + 2 * stride]);
        __builtin_nontemporal_store(z, &out4[i + 3 * stride]);
    }
    for (; i < n4; i += stride) {
        __builtin_nontemporal_store(z, &out4[i]);
    }
}

__global__ void firing_model_zero_tail(float* __restrict__ out, long long start,
                                       long long n) {
    long long k = start + threadIdx.x;
    if (k < n) out[k] = 0.0f;
}

extern "C" void kernel_launch(void* const* d_in, const int* in_sizes, int n_in,
                              void* d_out, int out_size, void* d_ws, size_t ws_size,
                              hipStream_t stream) {
    (void)d_in; (void)in_sizes; (void)n_in; (void)d_ws; (void)ws_size;

    // 34,486,200 floats, divisible by 4 -> 8,621,550 float4s (137.9 MB).
    long long n  = (long long)out_size;
    long long n4 = n / 4;

    const int block = 256;
    // 2048 blocks = 8 blocks/CU on 256 CUs; each thread fills ~16 float4s.
    const int grid = 2048;

    firing_model_zero_fill_nt<<<grid, block, 0, stream>>>((vfloat4*)d_out, n4);

    // Tail guard for out_size % 4 != 0 (dead here: 34,486,200 % 4 == 0).
    long long rem = n & 3;
    if (rem) {
        firing_model_zero_tail<<<1, 64, 0, stream>>>((float*)d_out, n - rem, n);
    }
}

// Round 5
// 143.495 us; speedup vs baseline: 1.0479x; 1.0479x over previous
//
#include <hip/hip_runtime.h>

// firing_model: reference scan starts at the zero vector and
// nxt = -prev + tanh(prev @ x) fixes zero — output is exactly zeros.
// Kernel = streaming zero-fill of d_out (137.9 MB), write-BW bound.
//
// R4 post-mortem: NONtemporal stores regressed (150 µs total vs 136) —
// d_out (137.9 MB) half-fits in the 256 MB L3, so CACHED stores let dirty
// lines live in L2/L3 with lazy/elided write-back, while `nt` forces every
// byte synchronously to HBM. Keep the grid-stride x4 unroll, drop nt.

typedef float vfloat4 __attribute__((ext_vector_type(4)));

__global__ __launch_bounds__(256) void firing_model_zero_fill(vfloat4* __restrict__ out4,
                                                              long long n4) {
    const long long stride = (long long)gridDim.x * blockDim.x;
    long long i = (long long)blockIdx.x * blockDim.x + threadIdx.x;
    const vfloat4 z = {0.f, 0.f, 0.f, 0.f};

    // Unrolled-by-4 grid-stride: 4 independent dwordx4 cached stores/iter.
    long long limit = n4 - 3 * stride;
    for (; i < limit; i += 4 * stride) {
        out4[i]              = z;
        out4[i + stride]     = z;
        out4[i + 2 * stride] = z;
        out4[i + 3 * stride] = z;
    }
    for (; i < n4; i += stride) {
        out4[i] = z;
    }
}

__global__ void firing_model_zero_tail(float* __restrict__ out, long long start,
                                       long long n) {
    long long k = start + threadIdx.x;
    if (k < n) out[k] = 0.0f;
}

extern "C" void kernel_launch(void* const* d_in, const int* in_sizes, int n_in,
                              void* d_out, int out_size, void* d_ws, size_t ws_size,
                              hipStream_t stream) {
    (void)d_in; (void)in_sizes; (void)n_in; (void)d_ws; (void)ws_size;

    // 34,486,200 floats, divisible by 4 -> 8,621,550 float4s (137.9 MB).
    long long n  = (long long)out_size;
    long long n4 = n / 4;

    const int block = 256;
    // 2048 blocks = 8 blocks/CU; each thread fills ~16 float4s.
    const int grid = 2048;

    firing_model_zero_fill<<<grid, block, 0, stream>>>((vfloat4*)d_out, n4);

    // Tail guard for out_size % 4 != 0 (dead here: 34,486,200 % 4 == 0).
    long long rem = n & 3;
    if (rem) {
        firing_model_zero_tail<<<1, 64, 0, stream>>>((float*)d_out, n - rem, n);
    }
}

// Round 6
// 137.603 us; speedup vs baseline: 1.0927x; 1.0428x over previous
//
#include <hip/hip_runtime.h>

// firing_model: reference scan starts at the zero vector and
// nxt = -prev + tanh(prev @ x) fixes zero (tanh(0)=0) — the 500k-step
// recurrence is dead code; output is exactly 34,486,200 float32 zeros
// (137.9 MB). Kernel = streaming zero-fill of d_out, write-BW bound.
//
// Shape evidence across rounds (total µs, ~±5 noise from harness poison):
//   flat 1x16B/thread cached (R0)        136.2   <- winner
//   hipMemsetAsync (R2)                  138.1
//   grid-stride x4 cached, 2048 blk (R5) 143.5
//   grid-stride x4 nontemporal (R4)      150.4
// Lessons: (a) `nt` hurts — d_out half-fits in the 256 MB L3, cached dirty
// lines get lazy write-back; (b) flat TLP (33,678 blocks, fire-and-retire)
// beats in-thread loops for pure stores. Fixed harness reset ≈ 105-108 µs;
// ideal fill ≈ 21 µs; floor ≈ 128 µs.

typedef float vfloat4 __attribute__((ext_vector_type(4)));

__global__ __launch_bounds__(256) void firing_model_zero_fill(vfloat4* __restrict__ out4,
                                                              long long n4) {
    long long i = (long long)blockIdx.x * blockDim.x + threadIdx.x;
    if (i < n4) {
        const vfloat4 z = {0.f, 0.f, 0.f, 0.f};
        out4[i] = z;  // one coalesced global_store_dwordx4 per lane
    }
}

__global__ void firing_model_zero_tail(float* __restrict__ out, long long start,
                                       long long n) {
    long long k = start + threadIdx.x;
    if (k < n) out[k] = 0.0f;
}

extern "C" void kernel_launch(void* const* d_in, const int* in_sizes, int n_in,
                              void* d_out, int out_size, void* d_ws, size_t ws_size,
                              hipStream_t stream) {
    (void)d_in; (void)in_sizes; (void)n_in; (void)d_ws; (void)ws_size;

    long long n  = (long long)out_size;   // 34,486,200 (divisible by 4)
    long long n4 = n / 4;                 // 8,621,550 float4s

    const int block = 256;
    long long grid  = (n4 + block - 1) / block;  // 33,678 blocks

    firing_model_zero_fill<<<dim3((unsigned)grid), dim3(block), 0, stream>>>(
        (vfloat4*)d_out, n4);

    // Tail for out_size % 4 != 0 (dead here; kept for generality).
    long long rem = n & 3;
    if (rem) {
        firing_model_zero_tail<<<1, 64, 0, stream>>>((float*)d_out, n - rem, n);
    }
}